// Round 14
// baseline (231.217 us; speedup 1.0000x reference)
//
#include <hip/hip_runtime.h>
#include <hip/hip_bf16.h>
#include <stdint.h>

// ---------------------------------------------------------------------------
// TensorNet: fused encoder MLP (128->256->256->256, relu) over 32x4096 tokens,
// per-batch mean -> p = relu(m^2) -> decoder MLP (256->512->512->10).
// Inputs/outputs fp32. Encoder via bf16 MFMA (A=weights M=hidden, B=act
// N=tokens) + fp32 accum.
// R13 FAILED: manual a-frag ping-pong regressed (MfmaUtil 25->22) — compiler
// already scheduled the L2-resident a-loads; reverted to R12 K-loop.
// R14: decoder node ELIMINATED. Per-batch done-counters: each encoder block,
// after its msum atomics are drained (syncthreads emits vmcnt(0)), does
// threadfence + atomicAdd(cnt[batch]); the last finisher (old==63) runs the
// batch's decoder inline (256 thr, LDS reused, msum read via atomicAdd(p,0)
// for L2-coherent reads). Dispatch-order-safe: no spin, no ordering assumed.
// 2 launch nodes total (pack -> encoder+tail).
// ---------------------------------------------------------------------------

#define NIN   128
#define NHID  256
#define NDEC  512
#define NOUTC 10
#define BATCH 32
#define NTOK  4096
#define MTILE 64
#define TPB   64               // encoder blocks per batch
#define NBLK  (BATCH * TPB)    // 2048 encoder tiles
#define XPAD  136              // x-tile LDS row stride (bf16)
#define HPAD  264              // h-tile LDS row stride (bf16)

typedef short bf16x8 __attribute__((ext_vector_type(8)));
typedef float floatx4 __attribute__((ext_vector_type(4)));

__device__ __forceinline__ uint16_t f2b(float f) {
  union { uint32_t u; float f; } v; v.f = f;
  uint32_t r = v.u + 0x7FFFu + ((v.u >> 16) & 1u);   // RNE
  return (uint16_t)(r >> 16);
}
__device__ __forceinline__ uint32_t pkbf(float lo, float hi) {
  __hip_bfloat162 h = __float22bfloat162_rn(float2{lo, hi});  // v_cvt_pk_bf16_f32
  union { __hip_bfloat162 h; uint32_t u; } c; c.h = h;
  return c.u;
}

// ---------------------------------------------------------------------------
// Pack W1/W2/W3 (fp32 [K][256] row-major) into bf16 MFMA-A-fragment order.
// Also zero-inits msum and the per-batch done-counters (0xAA-poisoned).
// ---------------------------------------------------------------------------
__global__ __launch_bounds__(256) void pack_weights(
    const float* __restrict__ W1, const float* __restrict__ W2,
    const float* __restrict__ W3, uint16_t* __restrict__ pW,
    float* __restrict__ msum, int* __restrict__ cnt) {
  int p = blockIdx.x * blockDim.x + threadIdx.x;
  if (p < BATCH * NHID) msum[p] = 0.f;
  if (p < BATCH) cnt[p] = 0;
  const float* W; int K; int base;
  if (p < 32768)      { W = W1; K = NIN;  base = 0; }
  else if (p < 98304) { W = W2; K = NHID; base = 32768; p -= 32768; }
  else                { W = W3; K = NHID; base = 98304; p -= 98304; }
  int j    = p & 7;
  int ln   = (p >> 3) & 63;
  int rest = p >> 9;
  int KC = K >> 5;
  int kc = rest % KC;
  int mt = rest / KC;
  int m = mt * 16 + (ln & 15);
  int k = kc * 32 + ((ln >> 4) << 3) + j;
  pW[base + (((mt * KC + kc) * 64 + ln) << 3) + j] = f2b(W[k * NHID + m]);
}

// ---------------------------------------------------------------------------
// Fused encoder + last-finisher decoder tail. Block = 256 thr (4 waves),
// 64 tokens. Wave w owns hidden rows [64w,64w+64) (A = packed weights);
// token tiles shared (B from LDS).
// NOTE: plain __launch_bounds__(256) — (256,4) forces VGPR=64 and spills
// the 64-VGPR accumulator (R5: +20MB HBM writes).
// ---------------------------------------------------------------------------
__global__ __launch_bounds__(256) void encoder(
    const float* __restrict__ x,        // [BATCH*NTOK][NIN] fp32
    const uint16_t* __restrict__ pW,
    const float* __restrict__ b1,
    const float* __restrict__ b2,
    const float* __restrict__ b3,
    float* __restrict__ msum,           // [BATCH][NHID] fp32 accum
    int* __restrict__ cnt,              // [BATCH] done counters
    const float* __restrict__ D1, const float* __restrict__ c1,
    const float* __restrict__ D2, const float* __restrict__ c2,
    const float* __restrict__ D3, const float* __restrict__ c3,
    float* __restrict__ out) {
  __shared__ __align__(16) uint16_t Hs[MTILE * HPAD];  // 33792 B
  __shared__ int lastFlag;

  const int tid  = threadIdx.x;
  const int wave = tid >> 6;
  const int lane = tid & 63;
  const int l15  = lane & 15;
  const int q    = lane >> 4;
  const int tok0  = blockIdx.x * MTILE;
  const int batch = blockIdx.x >> 6;

  const uint16_t* pW1 = pW;             // KC=4
  const uint16_t* pW2 = pW + 32768;     // KC=8
  const uint16_t* pW3 = pW + 98304;     // KC=8

  // ---- stage x tile: fp32 -> bf16, rows stride XPAD ----
  {
    const int row = tid >> 2;
    const int c0  = (tid & 3) * 32;
    const float* xr = x + (size_t)(tok0 + row) * NIN + c0;
    for (int i = 0; i < 8; ++i) {
      float4 v = *(const float4*)(xr + i * 4);
      uint2 u = make_uint2(pkbf(v.x, v.y), pkbf(v.z, v.w));
      *(uint2*)&Hs[row * XPAD + c0 + i * 4] = u;
    }
  }
  __syncthreads();

  floatx4 acc[4][4];   // [jt][tt]

  // ---- layer 1: K = 128, A = W1^T, B = x ----
  for (int jt = 0; jt < 4; ++jt)
    for (int tt = 0; tt < 4; ++tt)
      acc[jt][tt] = (floatx4){0.f, 0.f, 0.f, 0.f};
#pragma unroll
  for (int kc = 0; kc < 4; ++kc) {
    bf16x8 a[4], b[4];
#pragma unroll
    for (int jt = 0; jt < 4; ++jt)
      a[jt] = *(const bf16x8*)(pW1 + ((((wave * 4 + jt) * 4 + kc) * 64 + lane) << 3));
#pragma unroll
    for (int tt = 0; tt < 4; ++tt)
      b[tt] = *(const bf16x8*)&Hs[(tt * 16 + l15) * XPAD + kc * 32 + q * 8];
#pragma unroll
    for (int jt = 0; jt < 4; ++jt)
#pragma unroll
      for (int tt = 0; tt < 4; ++tt)
        acc[jt][tt] = __builtin_amdgcn_mfma_f32_16x16x32_bf16(
            a[jt], b[tt], acc[jt][tt], 0, 0, 0);
  }
  __syncthreads();   // x reads done before h1 overwrites

#pragma unroll
  for (int jt = 0; jt < 4; ++jt) {
    const int jbase = wave * 64 + jt * 16 + q * 4;
    const float4 bb = *(const float4*)&b1[jbase];
#pragma unroll
    for (int tt = 0; tt < 4; ++tt) {
      const int t = tt * 16 + l15;
      float v0 = fmaxf(acc[jt][tt][0] + bb.x, 0.f);
      float v1 = fmaxf(acc[jt][tt][1] + bb.y, 0.f);
      float v2 = fmaxf(acc[jt][tt][2] + bb.z, 0.f);
      float v3 = fmaxf(acc[jt][tt][3] + bb.w, 0.f);
      *(uint2*)&Hs[t * HPAD + jbase] = make_uint2(pkbf(v0, v1), pkbf(v2, v3));
    }
  }
  __syncthreads();

  // ---- layer 2: K = 256, A = W2^T, B = h1 ----
  for (int jt = 0; jt < 4; ++jt)
    for (int tt = 0; tt < 4; ++tt)
      acc[jt][tt] = (floatx4){0.f, 0.f, 0.f, 0.f};
#pragma unroll
  for (int kc = 0; kc < 8; ++kc) {
    bf16x8 a[4], b[4];
#pragma unroll
    for (int jt = 0; jt < 4; ++jt)
      a[jt] = *(const bf16x8*)(pW2 + ((((wave * 4 + jt) * 8 + kc) * 64 + lane) << 3));
#pragma unroll
    for (int tt = 0; tt < 4; ++tt)
      b[tt] = *(const bf16x8*)&Hs[(tt * 16 + l15) * HPAD + kc * 32 + q * 8];
#pragma unroll
    for (int jt = 0; jt < 4; ++jt)
#pragma unroll
      for (int tt = 0; tt < 4; ++tt)
        acc[jt][tt] = __builtin_amdgcn_mfma_f32_16x16x32_bf16(
            a[jt], b[tt], acc[jt][tt], 0, 0, 0);
  }
  __syncthreads();   // h1 reads done before overwrite
#pragma unroll
  for (int jt = 0; jt < 4; ++jt) {
    const int jbase = wave * 64 + jt * 16 + q * 4;
    const float4 bb = *(const float4*)&b2[jbase];
#pragma unroll
    for (int tt = 0; tt < 4; ++tt) {
      const int t = tt * 16 + l15;
      float v0 = fmaxf(acc[jt][tt][0] + bb.x, 0.f);
      float v1 = fmaxf(acc[jt][tt][1] + bb.y, 0.f);
      float v2 = fmaxf(acc[jt][tt][2] + bb.z, 0.f);
      float v3 = fmaxf(acc[jt][tt][3] + bb.w, 0.f);
      *(uint2*)&Hs[t * HPAD + jbase] = make_uint2(pkbf(v0, v1), pkbf(v2, v3));
    }
  }
  __syncthreads();

  // ---- layer 3: K = 256, A = W3^T, B = h2, fused token-sum ----
  for (int jt = 0; jt < 4; ++jt)
    for (int tt = 0; tt < 4; ++tt)
      acc[jt][tt] = (floatx4){0.f, 0.f, 0.f, 0.f};
#pragma unroll
  for (int kc = 0; kc < 8; ++kc) {
    bf16x8 a[4], b[4];
#pragma unroll
    for (int jt = 0; jt < 4; ++jt)
      a[jt] = *(const bf16x8*)(pW3 + ((((wave * 4 + jt) * 8 + kc) * 64 + lane) << 3));
#pragma unroll
    for (int tt = 0; tt < 4; ++tt)
      b[tt] = *(const bf16x8*)&Hs[(tt * 16 + l15) * HPAD + kc * 32 + q * 8];
#pragma unroll
    for (int jt = 0; jt < 4; ++jt)
#pragma unroll
      for (int tt = 0; tt < 4; ++tt)
        acc[jt][tt] = __builtin_amdgcn_mfma_f32_16x16x32_bf16(
            a[jt], b[tt], acc[jt][tt], 0, 0, 0);
  }
  __syncthreads();   // h2 reads done before scratch overwrites Hs

  // bias + relu + partial token-sum; scratch rows padded 17 float4 so the
  // final read's bank = (4c+4l+r)%32 (2-way, free) not (4l+r)%32 (16-way).
  {
    float4* scratch = (float4*)Hs;
#pragma unroll
    for (int jt = 0; jt < 4; ++jt) {
      const int jbase = wave * 64 + jt * 16 + q * 4;
      const float4 bb = *(const float4*)&b3[jbase];
      float s0 = 0.f, s1 = 0.f, s2 = 0.f, s3 = 0.f;
#pragma unroll
      for (int tt = 0; tt < 4; ++tt) {
        s0 += fmaxf(acc[jt][tt][0] + bb.x, 0.f);
        s1 += fmaxf(acc[jt][tt][1] + bb.y, 0.f);
        s2 += fmaxf(acc[jt][tt][2] + bb.z, 0.f);
        s3 += fmaxf(acc[jt][tt][3] + bb.w, 0.f);
      }
      scratch[((wave * 4 + jt) * 4 + q) * 17 + l15] = (float4){s0, s1, s2, s3};
    }
  }
  __syncthreads();
  {
    const int c = tid >> 2;
    const int r = tid & 3;
    const float* sf = (const float*)Hs;
    float v = 0.f;
#pragma unroll
    for (int l = 0; l < 16; ++l)
      v += sf[c * 68 + l * 4 + r];
    const int wv = c >> 4, jt = (c >> 2) & 3, qq = c & 3;
    const int j = wv * 64 + jt * 16 + qq * 4 + r;
    atomicAdd(&msum[batch * NHID + j], v);
  }

  // ======== last-finisher detection (dispatch-order-safe, no spin) ========
  __syncthreads();   // drains this block's msum atomics (vmcnt(0) at barrier)
  if (tid == 0) {
    __threadfence();                       // order msum atomics before cnt
    int old = atomicAdd(&cnt[batch], 1);
    lastFlag = (old == TPB - 1);
  }
  __syncthreads();
  if (!lastFlag) return;

  // ======== inline decoder for this batch (256 threads, LDS reused) =======
  // F layout: p[0,256) | d1[256,768) | d2[768,1280) | red[1280,2304)
  float* F   = (float*)Hs;
  float* p   = F;
  float* d1  = F + 256;
  float* d2  = F + 768;
  float* red = F + 1280;

  {
    // coherent read: msum written only by device-scope atomics (L2-resident)
    float m = atomicAdd(&msum[batch * NHID + tid], 0.f) * (1.f / NTOK);
    p[tid] = m * m;                      // relu(m^2) == m^2
  }
  __syncthreads();

  const int jg = tid & 127;              // j-group of 4 floats
  const int ks = tid >> 7;               // 2-way K-split

  // ---- dec layer 1: [256]x[256,512] ----
  {
    const float4* D1v = (const float4*)D1;   // [256][128] float4
    float4 s = {0.f, 0.f, 0.f, 0.f};
#pragma unroll 4
    for (int k = ks * 128; k < ks * 128 + 128; ++k) {
      float4 w = D1v[k * 128 + jg];
      float pv = p[k];
      s.x += pv * w.x; s.y += pv * w.y; s.z += pv * w.z; s.w += pv * w.w;
    }
    *(float4*)&red[tid * 4] = s;         // red[ks*512 + jg*4 + c]
    __syncthreads();
#pragma unroll
    for (int jj = 0; jj < 2; ++jj) {
      int j = tid + jj * 256;
      d1[j] = fmaxf(c1[j] + red[j] + red[512 + j], 0.f);
    }
    __syncthreads();
  }

  // ---- dec layer 2: [512]x[512,512] ----
  {
    const float4* D2v = (const float4*)D2;   // [512][128] float4
    float4 s = {0.f, 0.f, 0.f, 0.f};
#pragma unroll 4
    for (int k = ks * 256; k < ks * 256 + 256; ++k) {
      float4 w = D2v[k * 128 + jg];
      float hv = d1[k];
      s.x += hv * w.x; s.y += hv * w.y; s.z += hv * w.z; s.w += hv * w.w;
    }
    *(float4*)&red[tid * 4] = s;
    __syncthreads();
#pragma unroll
    for (int jj = 0; jj < 2; ++jj) {
      int j = tid + jj * 256;
      d2[j] = fmaxf(c2[j] + red[j] + red[512 + j], 0.f);
    }
    __syncthreads();
  }

  // ---- dec layer 3: [512]x[512,10] ----
  {
    const int j3 = tid & 15;             // 16 slots, 10 valid
    const int kc = tid >> 4;             // 16 chunks x 32 k
    float s = 0.f;
    if (j3 < NOUTC)
      for (int k = kc * 32; k < kc * 32 + 32; ++k)
        s += d2[k] * D3[k * NOUTC + j3];
    red[tid] = s;
    __syncthreads();
    if (tid < NOUTC) {
      float v = c3[tid];
#pragma unroll
      for (int i = 0; i < 16; ++i) v += red[i * 16 + tid];
      out[batch * NOUTC + tid] = v;
    }
  }
}

// ---------------------------------------------------------------------------
extern "C" void kernel_launch(void* const* d_in, const int* in_sizes, int n_in,
                              void* d_out, int out_size, void* d_ws, size_t ws_size,
                              hipStream_t stream) {
  const float* x  = (const float*)d_in[0];
  const float* W1 = (const float*)d_in[1];
  const float* b1 = (const float*)d_in[2];
  const float* W2 = (const float*)d_in[3];
  const float* b2 = (const float*)d_in[4];
  const float* W3 = (const float*)d_in[5];
  const float* b3 = (const float*)d_in[6];
  const float* D1 = (const float*)d_in[7];
  const float* c1 = (const float*)d_in[8];
  const float* D2 = (const float*)d_in[9];
  const float* c2 = (const float*)d_in[10];
  const float* D3 = (const float*)d_in[11];
  const float* c3 = (const float*)d_in[12];

  // ws: [0,320K) packed bf16 W | [384K,416K) msum | [416K,+128) cnt
  uint16_t* pW   = (uint16_t*)d_ws;
  float*    msum = (float*)((char*)d_ws + 384 * 1024);
  int*      cnt  = (int*)((char*)d_ws + 416 * 1024);

  pack_weights<<<640, 256, 0, stream>>>(W1, W2, W3, pW, msum, cnt);
  encoder<<<NBLK, 256, 0, stream>>>(x, pW, b1, b2, b3, msum, cnt,
                                    D1, c1, D2, c2, D3, c3, (float*)d_out);
}

// Round 15
// 207.143 us; speedup vs baseline: 1.1162x; 1.1162x over previous
//
#include <hip/hip_runtime.h>
#include <hip/hip_bf16.h>
#include <stdint.h>

// ---------------------------------------------------------------------------
// TensorNet: fused encoder MLP (128->256->256->256, relu) over 32x4096 tokens,
// per-batch mean -> p = relu(m^2) -> decoder MLP (256->512->512->10).
// Inputs/outputs fp32. Encoder via bf16 MFMA (A=weights M=hidden, B=act
// N=tokens) + fp32 accum. 2 launch nodes: pack -> encoder+decoder-tail.
// R14 FAILED: per-block __threadfence() (device-scope fence on multi-XCD
// gfx950 = L2 writeback+invalidate) evicted the L2-resident weights for all
// 2048 blocks -> MfmaUtil 25->11%, encoder 67->146us.
// R15: fence REMOVED. Safe because all cross-block traffic is device-scope
// atomics (coherent-point serialized, cache-bypassing): msum atomicAdd ->
// __syncthreads (emits s_waitcnt vmcnt(0), drains atomics) -> cnt atomicAdd.
// Last finisher (old==63) runs the batch's decoder inline, reading msum via
// atomicAdd(p, 0.f) (coherent read). No spin, no dispatch-order assumption.
// ---------------------------------------------------------------------------

#define NIN   128
#define NHID  256
#define NDEC  512
#define NOUTC 10
#define BATCH 32
#define NTOK  4096
#define MTILE 64
#define TPB   64               // encoder blocks per batch
#define NBLK  (BATCH * TPB)    // 2048 encoder tiles
#define XPAD  136              // x-tile LDS row stride (bf16)
#define HPAD  264              // h-tile LDS row stride (bf16)

typedef short bf16x8 __attribute__((ext_vector_type(8)));
typedef float floatx4 __attribute__((ext_vector_type(4)));

__device__ __forceinline__ uint16_t f2b(float f) {
  union { uint32_t u; float f; } v; v.f = f;
  uint32_t r = v.u + 0x7FFFu + ((v.u >> 16) & 1u);   // RNE
  return (uint16_t)(r >> 16);
}
__device__ __forceinline__ uint32_t pkbf(float lo, float hi) {
  __hip_bfloat162 h = __float22bfloat162_rn(float2{lo, hi});  // v_cvt_pk_bf16_f32
  union { __hip_bfloat162 h; uint32_t u; } c; c.h = h;
  return c.u;
}

// ---------------------------------------------------------------------------
// Pack W1/W2/W3 (fp32 [K][256] row-major) into bf16 MFMA-A-fragment order.
// Also zero-inits msum and the per-batch done-counters (0xAA-poisoned).
// ---------------------------------------------------------------------------
__global__ __launch_bounds__(256) void pack_weights(
    const float* __restrict__ W1, const float* __restrict__ W2,
    const float* __restrict__ W3, uint16_t* __restrict__ pW,
    float* __restrict__ msum, int* __restrict__ cnt) {
  int p = blockIdx.x * blockDim.x + threadIdx.x;
  if (p < BATCH * NHID) msum[p] = 0.f;
  if (p < BATCH) cnt[p] = 0;
  const float* W; int K; int base;
  if (p < 32768)      { W = W1; K = NIN;  base = 0; }
  else if (p < 98304) { W = W2; K = NHID; base = 32768; p -= 32768; }
  else                { W = W3; K = NHID; base = 98304; p -= 98304; }
  int j    = p & 7;
  int ln   = (p >> 3) & 63;
  int rest = p >> 9;
  int KC = K >> 5;
  int kc = rest % KC;
  int mt = rest / KC;
  int m = mt * 16 + (ln & 15);
  int k = kc * 32 + ((ln >> 4) << 3) + j;
  pW[base + (((mt * KC + kc) * 64 + ln) << 3) + j] = f2b(W[k * NHID + m]);
}

// ---------------------------------------------------------------------------
// Fused encoder + last-finisher decoder tail. Block = 256 thr (4 waves),
// 64 tokens. Wave w owns hidden rows [64w,64w+64) (A = packed weights);
// token tiles shared (B from LDS).
// NOTE: plain __launch_bounds__(256) — (256,4) forces VGPR=64 and spills
// the 64-VGPR accumulator (R5: +20MB HBM writes).
// ---------------------------------------------------------------------------
__global__ __launch_bounds__(256) void encoder(
    const float* __restrict__ x,        // [BATCH*NTOK][NIN] fp32
    const uint16_t* __restrict__ pW,
    const float* __restrict__ b1,
    const float* __restrict__ b2,
    const float* __restrict__ b3,
    float* __restrict__ msum,           // [BATCH][NHID] fp32 accum
    int* __restrict__ cnt,              // [BATCH] done counters
    const float* __restrict__ D1, const float* __restrict__ c1,
    const float* __restrict__ D2, const float* __restrict__ c2,
    const float* __restrict__ D3, const float* __restrict__ c3,
    float* __restrict__ out) {
  __shared__ __align__(16) uint16_t Hs[MTILE * HPAD];  // 33792 B
  __shared__ int lastFlag;

  const int tid  = threadIdx.x;
  const int wave = tid >> 6;
  const int lane = tid & 63;
  const int l15  = lane & 15;
  const int q    = lane >> 4;
  const int tok0  = blockIdx.x * MTILE;
  const int batch = blockIdx.x >> 6;

  const uint16_t* pW1 = pW;             // KC=4
  const uint16_t* pW2 = pW + 32768;     // KC=8
  const uint16_t* pW3 = pW + 98304;     // KC=8

  // ---- stage x tile: fp32 -> bf16, rows stride XPAD ----
  {
    const int row = tid >> 2;
    const int c0  = (tid & 3) * 32;
    const float* xr = x + (size_t)(tok0 + row) * NIN + c0;
    for (int i = 0; i < 8; ++i) {
      float4 v = *(const float4*)(xr + i * 4);
      uint2 u = make_uint2(pkbf(v.x, v.y), pkbf(v.z, v.w));
      *(uint2*)&Hs[row * XPAD + c0 + i * 4] = u;
    }
  }
  __syncthreads();

  floatx4 acc[4][4];   // [jt][tt]

  // ---- layer 1: K = 128, A = W1^T, B = x ----
  for (int jt = 0; jt < 4; ++jt)
    for (int tt = 0; tt < 4; ++tt)
      acc[jt][tt] = (floatx4){0.f, 0.f, 0.f, 0.f};
#pragma unroll
  for (int kc = 0; kc < 4; ++kc) {
    bf16x8 a[4], b[4];
#pragma unroll
    for (int jt = 0; jt < 4; ++jt)
      a[jt] = *(const bf16x8*)(pW1 + ((((wave * 4 + jt) * 4 + kc) * 64 + lane) << 3));
#pragma unroll
    for (int tt = 0; tt < 4; ++tt)
      b[tt] = *(const bf16x8*)&Hs[(tt * 16 + l15) * XPAD + kc * 32 + q * 8];
#pragma unroll
    for (int jt = 0; jt < 4; ++jt)
#pragma unroll
      for (int tt = 0; tt < 4; ++tt)
        acc[jt][tt] = __builtin_amdgcn_mfma_f32_16x16x32_bf16(
            a[jt], b[tt], acc[jt][tt], 0, 0, 0);
  }
  __syncthreads();   // x reads done before h1 overwrites

#pragma unroll
  for (int jt = 0; jt < 4; ++jt) {
    const int jbase = wave * 64 + jt * 16 + q * 4;
    const float4 bb = *(const float4*)&b1[jbase];
#pragma unroll
    for (int tt = 0; tt < 4; ++tt) {
      const int t = tt * 16 + l15;
      float v0 = fmaxf(acc[jt][tt][0] + bb.x, 0.f);
      float v1 = fmaxf(acc[jt][tt][1] + bb.y, 0.f);
      float v2 = fmaxf(acc[jt][tt][2] + bb.z, 0.f);
      float v3 = fmaxf(acc[jt][tt][3] + bb.w, 0.f);
      *(uint2*)&Hs[t * HPAD + jbase] = make_uint2(pkbf(v0, v1), pkbf(v2, v3));
    }
  }
  __syncthreads();

  // ---- layer 2: K = 256, A = W2^T, B = h1 ----
  for (int jt = 0; jt < 4; ++jt)
    for (int tt = 0; tt < 4; ++tt)
      acc[jt][tt] = (floatx4){0.f, 0.f, 0.f, 0.f};
#pragma unroll
  for (int kc = 0; kc < 8; ++kc) {
    bf16x8 a[4], b[4];
#pragma unroll
    for (int jt = 0; jt < 4; ++jt)
      a[jt] = *(const bf16x8*)(pW2 + ((((wave * 4 + jt) * 8 + kc) * 64 + lane) << 3));
#pragma unroll
    for (int tt = 0; tt < 4; ++tt)
      b[tt] = *(const bf16x8*)&Hs[(tt * 16 + l15) * HPAD + kc * 32 + q * 8];
#pragma unroll
    for (int jt = 0; jt < 4; ++jt)
#pragma unroll
      for (int tt = 0; tt < 4; ++tt)
        acc[jt][tt] = __builtin_amdgcn_mfma_f32_16x16x32_bf16(
            a[jt], b[tt], acc[jt][tt], 0, 0, 0);
  }
  __syncthreads();   // h1 reads done before overwrite
#pragma unroll
  for (int jt = 0; jt < 4; ++jt) {
    const int jbase = wave * 64 + jt * 16 + q * 4;
    const float4 bb = *(const float4*)&b2[jbase];
#pragma unroll
    for (int tt = 0; tt < 4; ++tt) {
      const int t = tt * 16 + l15;
      float v0 = fmaxf(acc[jt][tt][0] + bb.x, 0.f);
      float v1 = fmaxf(acc[jt][tt][1] + bb.y, 0.f);
      float v2 = fmaxf(acc[jt][tt][2] + bb.z, 0.f);
      float v3 = fmaxf(acc[jt][tt][3] + bb.w, 0.f);
      *(uint2*)&Hs[t * HPAD + jbase] = make_uint2(pkbf(v0, v1), pkbf(v2, v3));
    }
  }
  __syncthreads();

  // ---- layer 3: K = 256, A = W3^T, B = h2, fused token-sum ----
  for (int jt = 0; jt < 4; ++jt)
    for (int tt = 0; tt < 4; ++tt)
      acc[jt][tt] = (floatx4){0.f, 0.f, 0.f, 0.f};
#pragma unroll
  for (int kc = 0; kc < 8; ++kc) {
    bf16x8 a[4], b[4];
#pragma unroll
    for (int jt = 0; jt < 4; ++jt)
      a[jt] = *(const bf16x8*)(pW3 + ((((wave * 4 + jt) * 8 + kc) * 64 + lane) << 3));
#pragma unroll
    for (int tt = 0; tt < 4; ++tt)
      b[tt] = *(const bf16x8*)&Hs[(tt * 16 + l15) * HPAD + kc * 32 + q * 8];
#pragma unroll
    for (int jt = 0; jt < 4; ++jt)
#pragma unroll
      for (int tt = 0; tt < 4; ++tt)
        acc[jt][tt] = __builtin_amdgcn_mfma_f32_16x16x32_bf16(
            a[jt], b[tt], acc[jt][tt], 0, 0, 0);
  }
  __syncthreads();   // h2 reads done before scratch overwrites Hs

  // bias + relu + partial token-sum; scratch rows padded 17 float4 so the
  // final read's bank = (4c+4l+r)%32 (2-way, free) not (4l+r)%32 (16-way).
  {
    float4* scratch = (float4*)Hs;
#pragma unroll
    for (int jt = 0; jt < 4; ++jt) {
      const int jbase = wave * 64 + jt * 16 + q * 4;
      const float4 bb = *(const float4*)&b3[jbase];
      float s0 = 0.f, s1 = 0.f, s2 = 0.f, s3 = 0.f;
#pragma unroll
      for (int tt = 0; tt < 4; ++tt) {
        s0 += fmaxf(acc[jt][tt][0] + bb.x, 0.f);
        s1 += fmaxf(acc[jt][tt][1] + bb.y, 0.f);
        s2 += fmaxf(acc[jt][tt][2] + bb.z, 0.f);
        s3 += fmaxf(acc[jt][tt][3] + bb.w, 0.f);
      }
      scratch[((wave * 4 + jt) * 4 + q) * 17 + l15] = (float4){s0, s1, s2, s3};
    }
  }
  __syncthreads();
  {
    const int c = tid >> 2;
    const int r = tid & 3;
    const float* sf = (const float*)Hs;
    float v = 0.f;
#pragma unroll
    for (int l = 0; l < 16; ++l)
      v += sf[c * 68 + l * 4 + r];
    const int wv = c >> 4, jt = (c >> 2) & 3, qq = c & 3;
    const int j = wv * 64 + jt * 16 + qq * 4 + r;
    atomicAdd(&msum[batch * NHID + j], v);
  }

  // ======== last-finisher detection (dispatch-order-safe, no spin) ========
  // __syncthreads drains this block's msum atomics to the coherent point
  // (s_waitcnt vmcnt(0) before s_barrier). cnt and msum are both device-
  // scope atomics serialized at the coherent point -> no cache fence needed
  // (R14's __threadfence invalidated L2 per block: 67->146us. Never again.)
  __syncthreads();
  if (tid == 0) {
    int old = atomicAdd(&cnt[batch], 1);
    lastFlag = (old == TPB - 1);
  }
  __syncthreads();
  if (!lastFlag) return;

  // ======== inline decoder for this batch (256 threads, LDS reused) =======
  // F layout: p[0,256) | d1[256,768) | d2[768,1280) | red[1280,2304)
  float* F   = (float*)Hs;
  float* p   = F;
  float* d1  = F + 256;
  float* d2  = F + 768;
  float* red = F + 1280;

  {
    // coherent read: msum written only by device-scope atomics
    float m = atomicAdd(&msum[batch * NHID + tid], 0.f) * (1.f / NTOK);
    p[tid] = m * m;                      // relu(m^2) == m^2
  }
  __syncthreads();

  const int jg = tid & 127;              // j-group of 4 floats
  const int ks = tid >> 7;               // 2-way K-split

  // ---- dec layer 1: [256]x[256,512] ----
  {
    const float4* D1v = (const float4*)D1;   // [256][128] float4
    float4 s = {0.f, 0.f, 0.f, 0.f};
#pragma unroll 4
    for (int k = ks * 128; k < ks * 128 + 128; ++k) {
      float4 w = D1v[k * 128 + jg];
      float pv = p[k];
      s.x += pv * w.x; s.y += pv * w.y; s.z += pv * w.z; s.w += pv * w.w;
    }
    *(float4*)&red[tid * 4] = s;         // red[ks*512 + jg*4 + c]
    __syncthreads();
#pragma unroll
    for (int jj = 0; jj < 2; ++jj) {
      int j = tid + jj * 256;
      d1[j] = fmaxf(c1[j] + red[j] + red[512 + j], 0.f);
    }
    __syncthreads();
  }

  // ---- dec layer 2: [512]x[512,512] ----
  {
    const float4* D2v = (const float4*)D2;   // [512][128] float4
    float4 s = {0.f, 0.f, 0.f, 0.f};
#pragma unroll 4
    for (int k = ks * 256; k < ks * 256 + 256; ++k) {
      float4 w = D2v[k * 128 + jg];
      float hv = d1[k];
      s.x += hv * w.x; s.y += hv * w.y; s.z += hv * w.z; s.w += hv * w.w;
    }
    *(float4*)&red[tid * 4] = s;
    __syncthreads();
#pragma unroll
    for (int jj = 0; jj < 2; ++jj) {
      int j = tid + jj * 256;
      d2[j] = fmaxf(c2[j] + red[j] + red[512 + j], 0.f);
    }
    __syncthreads();
  }

  // ---- dec layer 3: [512]x[512,10] ----
  {
    const int j3 = tid & 15;             // 16 slots, 10 valid
    const int kc = tid >> 4;             // 16 chunks x 32 k
    float s = 0.f;
    if (j3 < NOUTC)
      for (int k = kc * 32; k < kc * 32 + 32; ++k)
        s += d2[k] * D3[k * NOUTC + j3];
    red[tid] = s;
    __syncthreads();
    if (tid < NOUTC) {
      float v = c3[tid];
#pragma unroll
      for (int i = 0; i < 16; ++i) v += red[i * 16 + tid];
      out[batch * NOUTC + tid] = v;
    }
  }
}

// ---------------------------------------------------------------------------
extern "C" void kernel_launch(void* const* d_in, const int* in_sizes, int n_in,
                              void* d_out, int out_size, void* d_ws, size_t ws_size,
                              hipStream_t stream) {
  const float* x  = (const float*)d_in[0];
  const float* W1 = (const float*)d_in[1];
  const float* b1 = (const float*)d_in[2];
  const float* W2 = (const float*)d_in[3];
  const float* b2 = (const float*)d_in[4];
  const float* W3 = (const float*)d_in[5];
  const float* b3 = (const float*)d_in[6];
  const float* D1 = (const float*)d_in[7];
  const float* c1 = (const float*)d_in[8];
  const float* D2 = (const float*)d_in[9];
  const float* c2 = (const float*)d_in[10];
  const float* D3 = (const float*)d_in[11];
  const float* c3 = (const float*)d_in[12];

  // ws: [0,320K) packed bf16 W | [384K,416K) msum | [416K,+128) cnt
  uint16_t* pW   = (uint16_t*)d_ws;
  float*    msum = (float*)((char*)d_ws + 384 * 1024);
  int*      cnt  = (int*)((char*)d_ws + 416 * 1024);

  pack_weights<<<640, 256, 0, stream>>>(W1, W2, W3, pW, msum, cnt);
  encoder<<<NBLK, 256, 0, stream>>>(x, pW, b1, b2, b3, msum, cnt,
                                    D1, c1, D2, c2, D3, c3, (float*)d_out);
}

// Round 16
// 172.705 us; speedup vs baseline: 1.3388x; 1.1994x over previous
//
#include <hip/hip_runtime.h>
#include <hip/hip_bf16.h>
#include <stdint.h>

// ---------------------------------------------------------------------------
// TensorNet: fused encoder MLP (128->256->256->256, relu) over 32x4096 tokens,
// per-batch mean -> p = relu(m^2) -> decoder MLP (256->512->512->10).
// Inputs/outputs fp32. Encoder via bf16 MFMA (A=weights M=hidden, B=act
// N=tokens) + fp32 accum. THIS IS THE R12 CONFIGURATION (best measured:
// 173.4us) — locked in after R13-R15 regressions.
//
// Explored & rejected (evidence in session log):
//  - __launch_bounds__(256,4): VGPR forced to 64 < acc live-set -> spills
//    (+20MB HBM writes, R5).
//  - direct-global layer-1 B-frags + shfl butterfly reduce: 4x-redundant
//    x reads beat the barriers saved (R5/R6, 93-96us vs 66us).
//  - manual a-frag ping-pong pipeline: compiler already schedules the
//    L2-resident a-loads; added VALU overhead (R13, 78us).
//  - cooperative single-kernel: VGPR 92->176 (378us) AND coop launch fails
//    under graph capture -> can never be the timed path (R11).
//  - fusing decoder as last-finisher tail into encoder: encoder dispatch
//    67->140us, occupancy -40%, with or without __threadfence (R14/R15) —
//    mechanism unresolved, cost >> the ~20us node saved. 3 nodes is final.
// ---------------------------------------------------------------------------

#define NIN   128
#define NHID  256
#define NDEC  512
#define NOUTC 10
#define BATCH 32
#define NTOK  4096
#define MTILE 64
#define NBLK  (BATCH * (NTOK / MTILE))   // 2048 encoder tiles
#define XPAD  136                         // x-tile LDS row stride (bf16)
#define HPAD  264                         // h-tile LDS row stride (bf16)

typedef short bf16x8 __attribute__((ext_vector_type(8)));
typedef float floatx4 __attribute__((ext_vector_type(4)));

__device__ __forceinline__ uint16_t f2b(float f) {
  union { uint32_t u; float f; } v; v.f = f;
  uint32_t r = v.u + 0x7FFFu + ((v.u >> 16) & 1u);   // RNE
  return (uint16_t)(r >> 16);
}
__device__ __forceinline__ uint32_t pkbf(float lo, float hi) {
  __hip_bfloat162 h = __float22bfloat162_rn(float2{lo, hi});  // v_cvt_pk_bf16_f32
  union { __hip_bfloat162 h; uint32_t u; } c; c.h = h;
  return c.u;
}

// ---------------------------------------------------------------------------
// Pack W1/W2/W3 (fp32 [K][256] row-major) into bf16 MFMA-A-fragment order.
// Also zero-inits msum (poisoned 0xAA by the harness).
// ---------------------------------------------------------------------------
__global__ __launch_bounds__(256) void pack_weights(
    const float* __restrict__ W1, const float* __restrict__ W2,
    const float* __restrict__ W3, uint16_t* __restrict__ pW,
    float* __restrict__ msum) {
  int p = blockIdx.x * blockDim.x + threadIdx.x;
  if (p < BATCH * NHID) msum[p] = 0.f;
  const float* W; int K; int base;
  if (p < 32768)      { W = W1; K = NIN;  base = 0; }
  else if (p < 98304) { W = W2; K = NHID; base = 32768; p -= 32768; }
  else                { W = W3; K = NHID; base = 98304; p -= 98304; }
  int j    = p & 7;
  int ln   = (p >> 3) & 63;
  int rest = p >> 9;
  int KC = K >> 5;
  int kc = rest % KC;
  int mt = rest / KC;
  int m = mt * 16 + (ln & 15);
  int k = kc * 32 + ((ln >> 4) << 3) + j;
  pW[base + (((mt * KC + kc) * 64 + ln) << 3) + j] = f2b(W[k * NHID + m]);
}

// ---------------------------------------------------------------------------
// Fused encoder. Block = 256 thr (4 waves), 64 tokens. Wave w owns hidden
// rows [64w,64w+64) (A = packed weights); token tiles shared (B from LDS).
// NOTE: plain __launch_bounds__(256) — (256,4) forces VGPR=64 and spills
// the 64-VGPR accumulator (R5: +20MB HBM writes).
// ---------------------------------------------------------------------------
__global__ __launch_bounds__(256) void encoder(
    const float* __restrict__ x,        // [BATCH*NTOK][NIN] fp32
    const uint16_t* __restrict__ pW,
    const float* __restrict__ b1,
    const float* __restrict__ b2,
    const float* __restrict__ b3,
    float* __restrict__ msum) {         // [BATCH][NHID] fp32 accum
  __shared__ __align__(16) uint16_t Hs[MTILE * HPAD];  // 33792 B

  const int tid  = threadIdx.x;
  const int wave = tid >> 6;
  const int lane = tid & 63;
  const int l15  = lane & 15;
  const int q    = lane >> 4;
  const int tok0  = blockIdx.x * MTILE;
  const int batch = blockIdx.x >> 6;

  const uint16_t* pW1 = pW;             // KC=4
  const uint16_t* pW2 = pW + 32768;     // KC=8
  const uint16_t* pW3 = pW + 98304;     // KC=8

  // ---- stage x tile: fp32 -> bf16, rows stride XPAD ----
  {
    const int row = tid >> 2;
    const int c0  = (tid & 3) * 32;
    const float* xr = x + (size_t)(tok0 + row) * NIN + c0;
    for (int i = 0; i < 8; ++i) {
      float4 v = *(const float4*)(xr + i * 4);
      uint2 u = make_uint2(pkbf(v.x, v.y), pkbf(v.z, v.w));
      *(uint2*)&Hs[row * XPAD + c0 + i * 4] = u;
    }
  }
  __syncthreads();

  floatx4 acc[4][4];   // [jt][tt]

  // ---- layer 1: K = 128, A = W1^T, B = x ----
  for (int jt = 0; jt < 4; ++jt)
    for (int tt = 0; tt < 4; ++tt)
      acc[jt][tt] = (floatx4){0.f, 0.f, 0.f, 0.f};
#pragma unroll
  for (int kc = 0; kc < 4; ++kc) {
    bf16x8 a[4], b[4];
#pragma unroll
    for (int jt = 0; jt < 4; ++jt)
      a[jt] = *(const bf16x8*)(pW1 + ((((wave * 4 + jt) * 4 + kc) * 64 + lane) << 3));
#pragma unroll
    for (int tt = 0; tt < 4; ++tt)
      b[tt] = *(const bf16x8*)&Hs[(tt * 16 + l15) * XPAD + kc * 32 + q * 8];
#pragma unroll
    for (int jt = 0; jt < 4; ++jt)
#pragma unroll
      for (int tt = 0; tt < 4; ++tt)
        acc[jt][tt] = __builtin_amdgcn_mfma_f32_16x16x32_bf16(
            a[jt], b[tt], acc[jt][tt], 0, 0, 0);
  }
  __syncthreads();   // x reads done before h1 overwrites

#pragma unroll
  for (int jt = 0; jt < 4; ++jt) {
    const int jbase = wave * 64 + jt * 16 + q * 4;
    const float4 bb = *(const float4*)&b1[jbase];
#pragma unroll
    for (int tt = 0; tt < 4; ++tt) {
      const int t = tt * 16 + l15;
      float v0 = fmaxf(acc[jt][tt][0] + bb.x, 0.f);
      float v1 = fmaxf(acc[jt][tt][1] + bb.y, 0.f);
      float v2 = fmaxf(acc[jt][tt][2] + bb.z, 0.f);
      float v3 = fmaxf(acc[jt][tt][3] + bb.w, 0.f);
      *(uint2*)&Hs[t * HPAD + jbase] = make_uint2(pkbf(v0, v1), pkbf(v2, v3));
    }
  }
  __syncthreads();

  // ---- layer 2: K = 256, A = W2^T, B = h1 ----
  for (int jt = 0; jt < 4; ++jt)
    for (int tt = 0; tt < 4; ++tt)
      acc[jt][tt] = (floatx4){0.f, 0.f, 0.f, 0.f};
#pragma unroll
  for (int kc = 0; kc < 8; ++kc) {
    bf16x8 a[4], b[4];
#pragma unroll
    for (int jt = 0; jt < 4; ++jt)
      a[jt] = *(const bf16x8*)(pW2 + ((((wave * 4 + jt) * 8 + kc) * 64 + lane) << 3));
#pragma unroll
    for (int tt = 0; tt < 4; ++tt)
      b[tt] = *(const bf16x8*)&Hs[(tt * 16 + l15) * HPAD + kc * 32 + q * 8];
#pragma unroll
    for (int jt = 0; jt < 4; ++jt)
#pragma unroll
      for (int tt = 0; tt < 4; ++tt)
        acc[jt][tt] = __builtin_amdgcn_mfma_f32_16x16x32_bf16(
            a[jt], b[tt], acc[jt][tt], 0, 0, 0);
  }
  __syncthreads();   // h1 reads done before overwrite
#pragma unroll
  for (int jt = 0; jt < 4; ++jt) {
    const int jbase = wave * 64 + jt * 16 + q * 4;
    const float4 bb = *(const float4*)&b2[jbase];
#pragma unroll
    for (int tt = 0; tt < 4; ++tt) {
      const int t = tt * 16 + l15;
      float v0 = fmaxf(acc[jt][tt][0] + bb.x, 0.f);
      float v1 = fmaxf(acc[jt][tt][1] + bb.y, 0.f);
      float v2 = fmaxf(acc[jt][tt][2] + bb.z, 0.f);
      float v3 = fmaxf(acc[jt][tt][3] + bb.w, 0.f);
      *(uint2*)&Hs[t * HPAD + jbase] = make_uint2(pkbf(v0, v1), pkbf(v2, v3));
    }
  }
  __syncthreads();

  // ---- layer 3: K = 256, A = W3^T, B = h2, fused token-sum ----
  for (int jt = 0; jt < 4; ++jt)
    for (int tt = 0; tt < 4; ++tt)
      acc[jt][tt] = (floatx4){0.f, 0.f, 0.f, 0.f};
#pragma unroll
  for (int kc = 0; kc < 8; ++kc) {
    bf16x8 a[4], b[4];
#pragma unroll
    for (int jt = 0; jt < 4; ++jt)
      a[jt] = *(const bf16x8*)(pW3 + ((((wave * 4 + jt) * 8 + kc) * 64 + lane) << 3));
#pragma unroll
    for (int tt = 0; tt < 4; ++tt)
      b[tt] = *(const bf16x8*)&Hs[(tt * 16 + l15) * HPAD + kc * 32 + q * 8];
#pragma unroll
    for (int jt = 0; jt < 4; ++jt)
#pragma unroll
      for (int tt = 0; tt < 4; ++tt)
        acc[jt][tt] = __builtin_amdgcn_mfma_f32_16x16x32_bf16(
            a[jt], b[tt], acc[jt][tt], 0, 0, 0);
  }
  __syncthreads();   // h2 reads done before scratch overwrites Hs

  // bias + relu + partial token-sum; scratch rows padded 17 float4 so the
  // final read's bank = (4c+4l+r)%32 (2-way, free) not (4l+r)%32 (16-way).
  {
    float4* scratch = (float4*)Hs;
#pragma unroll
    for (int jt = 0; jt < 4; ++jt) {
      const int jbase = wave * 64 + jt * 16 + q * 4;
      const float4 bb = *(const float4*)&b3[jbase];
      float s0 = 0.f, s1 = 0.f, s2 = 0.f, s3 = 0.f;
#pragma unroll
      for (int tt = 0; tt < 4; ++tt) {
        s0 += fmaxf(acc[jt][tt][0] + bb.x, 0.f);
        s1 += fmaxf(acc[jt][tt][1] + bb.y, 0.f);
        s2 += fmaxf(acc[jt][tt][2] + bb.z, 0.f);
        s3 += fmaxf(acc[jt][tt][3] + bb.w, 0.f);
      }
      scratch[((wave * 4 + jt) * 4 + q) * 17 + l15] = (float4){s0, s1, s2, s3};
    }
  }
  __syncthreads();
  {
    const int c = tid >> 2;
    const int r = tid & 3;
    const float* sf = (const float*)Hs;
    float v = 0.f;
#pragma unroll
    for (int l = 0; l < 16; ++l)
      v += sf[c * 68 + l * 4 + r];
    const int wv = c >> 4, jt = (c >> 2) & 3, qq = c & 3;
    const int j = wv * 64 + jt * 16 + qq * 4 + r;
    atomicAdd(&msum[batch * NHID + j], v);
  }
}

// ---------------------------------------------------------------------------
// Decoder: one block per batch, 1024 threads; 4-wide j-vectorization +
// 8-way K-split (R12).
// ---------------------------------------------------------------------------
__global__ __launch_bounds__(1024) void decoder(
    const float* __restrict__ msum,
    const float* __restrict__ D1, const float* __restrict__ c1,
    const float* __restrict__ D2, const float* __restrict__ c2,
    const float* __restrict__ D3, const float* __restrict__ c3,
    float* __restrict__ out) {
  __shared__ float p[NHID];
  __shared__ float d1[NDEC];
  __shared__ float d2[NDEC];
  __shared__ __align__(16) float red[4096];   // 16 KB
  const int b = blockIdx.x, t = threadIdx.x;

  if (t < NHID) {
    float m = msum[b * NHID + t] * (1.f / NTOK);
    p[t] = m * m;                        // relu(m^2) == m^2
  }
  __syncthreads();

  const int jg = t & 127;                // j-group of 4
  const int ks = t >> 7;                 // 0..7 K-split

  // ---- layer 1: K = 256 -> 32 k per split ----
  {
    const float4* D1v = (const float4*)D1;   // [256][128] float4
    float4 s = {0.f, 0.f, 0.f, 0.f};
    for (int k = ks * 32; k < ks * 32 + 32; ++k) {
      float4 w = D1v[k * 128 + jg];
      float pv = p[k];
      s.x += pv * w.x; s.y += pv * w.y; s.z += pv * w.z; s.w += pv * w.w;
    }
    *(float4*)&red[t * 4] = s;
    __syncthreads();
    if (t < NDEC) {
      float v = c1[t];
#pragma unroll
      for (int i = 0; i < 8; ++i) v += red[i * 512 + t];
      d1[t] = fmaxf(v, 0.f);
    }
    __syncthreads();
  }

  // ---- layer 2: K = 512 -> 64 k per split ----
  {
    const float4* D2v = (const float4*)D2;   // [512][128] float4
    float4 s = {0.f, 0.f, 0.f, 0.f};
    for (int k = ks * 64; k < ks * 64 + 64; ++k) {
      float4 w = D2v[k * 128 + jg];
      float hv = d1[k];
      s.x += hv * w.x; s.y += hv * w.y; s.z += hv * w.z; s.w += hv * w.w;
    }
    *(float4*)&red[t * 4] = s;
    __syncthreads();
    if (t < NDEC) {
      float v = c2[t];
#pragma unroll
      for (int i = 0; i < 8; ++i) v += red[i * 512 + t];
      d2[t] = fmaxf(v, 0.f);
    }
    __syncthreads();
  }

  // ---- layer 3: [512][10]; 64 k-chunks x 16 j-slots (10 valid) ----
  {
    const int j3 = t & 15;
    const int kc = t >> 4;               // 0..63, 8 k's each
    float s = 0.f;
    if (j3 < NOUTC)
      for (int k = kc * 8; k < kc * 8 + 8; ++k)
        s += d2[k] * D3[k * NOUTC + j3];
    red[t] = s;
    __syncthreads();
    if (t < NOUTC) {
      float v = c3[t];
#pragma unroll
      for (int i = 0; i < 64; ++i) v += red[i * 16 + t];
      out[b * NOUTC + t] = v;
    }
  }
}

// ---------------------------------------------------------------------------
extern "C" void kernel_launch(void* const* d_in, const int* in_sizes, int n_in,
                              void* d_out, int out_size, void* d_ws, size_t ws_size,
                              hipStream_t stream) {
  const float* x  = (const float*)d_in[0];
  const float* W1 = (const float*)d_in[1];
  const float* b1 = (const float*)d_in[2];
  const float* W2 = (const float*)d_in[3];
  const float* b2 = (const float*)d_in[4];
  const float* W3 = (const float*)d_in[5];
  const float* b3 = (const float*)d_in[6];
  const float* D1 = (const float*)d_in[7];
  const float* c1 = (const float*)d_in[8];
  const float* D2 = (const float*)d_in[9];
  const float* c2 = (const float*)d_in[10];
  const float* D3 = (const float*)d_in[11];
  const float* c3 = (const float*)d_in[12];

  // ws: [0,320K) packed bf16 W | [384K,416K) msum
  uint16_t* pW   = (uint16_t*)d_ws;
  float*    msum = (float*)((char*)d_ws + 384 * 1024);

  pack_weights<<<640, 256, 0, stream>>>(W1, W2, W3, pW, msum);
  encoder<<<NBLK, 256, 0, stream>>>(x, pW, b1, b2, b3, msum);
  decoder<<<BATCH, 1024, 0, stream>>>(msum, D1, c1, D2, c2, D3, c3,
                                      (float*)d_out);
}